// Round 1
// baseline (2772.946 us; speedup 1.0000x reference)
//
#include <hip/hip_runtime.h>
#include <math.h>

#define NB   256
#define NIMG 128
#define DIM  768
#define NE   3
#define NS   44
#define NH   1024
#define ESL  132          // NE*NS
#define NTOK (NB*NIMG)    // 32768
#define MAXSLOTS 88

// ---------------- helpers ----------------
__device__ __forceinline__ float gelu_f(float v) {
    return 0.5f * v * (1.0f + erff(v * 0.70710678118654752f));
}

__device__ __forceinline__ float block_reduce_sum256(float v, float* red) {
    int tid = threadIdx.x;
    red[tid] = v;
    __syncthreads();
    for (int s = 128; s > 0; s >>= 1) {
        if (tid < s) red[tid] += red[tid + s];
        __syncthreads();
    }
    float r = red[0];
    __syncthreads();
    return r;
}

// ---------------- repack mu: (e,d,88) -> Wt[d*132 + e*44 + s] ----------------
__global__ void repack_mu_k(const float* __restrict__ mu, float* __restrict__ wt) {
    int idx = blockIdx.x * 256 + threadIdx.x;
    if (idx >= DIM * ESL) return;
    int d = idx / ESL, r = idx - d * ESL;
    int e = r / NS, s = r - e * NS;
    wt[idx] = mu[((size_t)e * DIM + d) * MAXSLOTS + s];
}

// ---------------- slot_bias[b,:] = cls@vsg_w[:768] + af*vsg_w[768] + vsg_b ----------------
__global__ void slot_bias_k(const float* __restrict__ x, const float* __restrict__ aw,
                            const float* __restrict__ vsg_w, const float* __restrict__ vsg_b,
                            float* __restrict__ slot_bias) {
    __shared__ float red[256];
    __shared__ float cls[DIM];
    int b = blockIdx.x, tid = threadIdx.x;
    float a = (tid < NIMG) ? aw[b * NIMG + tid] : 0.f;
    float af = block_reduce_sum256(a, red) * (1.0f / NIMG);
    for (int j = tid; j < DIM; j += 256) cls[j] = x[(size_t)b * 129 * DIM + j];
    __syncthreads();
    int j0 = tid, j1 = tid + 256, j2 = tid + 512;
    float acc0 = 0.f, acc1 = 0.f, acc2 = 0.f;
    for (int d = 0; d < DIM; ++d) {
        float c = cls[d];
        const float* wr = vsg_w + (size_t)d * DIM;
        acc0 = fmaf(c, wr[j0], acc0);
        acc1 = fmaf(c, wr[j1], acc1);
        acc2 = fmaf(c, wr[j2], acc2);
    }
    const float* wl = vsg_w + (size_t)DIM * DIM;
    float* out = slot_bias + (size_t)b * DIM;
    out[j0] = acc0 + vsg_b[j0] + af * wl[j0];
    out[j1] = acc1 + vsg_b[j1] + af * wl[j1];
    out[j2] = acc2 + vsg_b[j2] + af * wl[j2];
}

// ---------------- LayerNorm + t2 = dot(img_n, slot_bias[b]) ----------------
__global__ void ln_t2_k(const float* __restrict__ x, const float* __restrict__ gamma,
                        const float* __restrict__ beta, const float* __restrict__ slot_bias,
                        float* __restrict__ img_n, float* __restrict__ t2) {
    __shared__ float red[256];
    int tok = blockIdx.x;
    int b = tok >> 7, n = tok & 127;
    int tid = threadIdx.x;
    const float* row = x + ((size_t)b * 129 + 1 + n) * DIM;
    float v0 = row[tid], v1 = row[tid + 256], v2 = row[tid + 512];
    float s  = block_reduce_sum256(v0 + v1 + v2, red);
    float ss = block_reduce_sum256(v0*v0 + v1*v1 + v2*v2, red);
    float mean = s * (1.0f / DIM);
    float var  = ss * (1.0f / DIM) - mean * mean;
    float inv  = rsqrtf(var + 1e-5f);
    const float* sb = slot_bias + (size_t)b * DIM;
    float* orow = img_n + (size_t)tok * DIM;
    float tacc = 0.f;
    int j = tid;
    float y0 = (v0 - mean) * inv * gamma[j] + beta[j]; orow[j] = y0; tacc = fmaf(y0, sb[j], tacc);
    j = tid + 256;
    float y1 = (v1 - mean) * inv * gamma[j] + beta[j]; orow[j] = y1; tacc = fmaf(y1, sb[j], tacc);
    j = tid + 512;
    float y2 = (v2 - mean) * inv * gamma[j] + beta[j]; orow[j] = y2; tacc = fmaf(y2, sb[j], tacc);
    float t = block_reduce_sum256(tacc, red);
    if (tid == 0) t2[tok] = t;
}

// ---------------- masked logits: L = (e==sel) ? scale*(t1+t2) : 0 ----------------
__global__ void mask_k(float* __restrict__ L, const float* __restrict__ t2,
                       const float* __restrict__ aw, const float* __restrict__ scale) {
    int idx = blockIdx.x * 256 + threadIdx.x;
    if (idx >= NTOK * ESL) return;
    int tok = idx / ESL, r = idx - tok * ESL;
    int e = r / NS;
    float a = aw[tok];
    int sel = (a > 0.7f) ? 0 : ((a >= 0.3f) ? 1 : 2);
    float v = 0.f;
    if (e == sel) v = scale[0] * (L[idx] + t2[tok]);
    L[idx] = v;
}

// ---------------- dispatch softmax over n (axis=1), output transposed [b, es, n] ----------------
__global__ void dispatch_k(const float* __restrict__ L, float* __restrict__ dT) {
    __shared__ float red[128];
    int es = blockIdx.x, b = blockIdx.y, tid = threadIdx.x;  // 128 threads
    float v = L[((size_t)(b * NIMG + tid)) * ESL + es];
    red[tid] = v; __syncthreads();
    for (int s = 64; s > 0; s >>= 1) { if (tid < s) red[tid] = fmaxf(red[tid], red[tid + s]); __syncthreads(); }
    float mx = red[0]; __syncthreads();
    float e = __expf(v - mx);
    red[tid] = e; __syncthreads();
    for (int s = 64; s > 0; s >>= 1) { if (tid < s) red[tid] += red[tid + s]; __syncthreads(); }
    float sum = red[0];
    dT[((size_t)b * ESL + es) * NIMG + tid] = e / sum;
}

// ---------------- combine softmax over es (132) per token ----------------
__global__ void combine_k(const float* __restrict__ L, float* __restrict__ C) {
    int tok = blockIdx.x, lane = threadIdx.x;  // 64 threads
    const float* row = L + (size_t)tok * ESL;
    float v0 = row[lane], v1 = row[lane + 64];
    bool has2 = lane < (ESL - 128);
    float v2 = has2 ? row[lane + 128] : -1e30f;
    float m = fmaxf(fmaxf(v0, v1), v2);
    for (int o = 32; o > 0; o >>= 1) m = fmaxf(m, __shfl_xor(m, o));
    float e0 = __expf(v0 - m), e1 = __expf(v1 - m);
    float e2 = has2 ? __expf(v2 - m) : 0.f;
    float s = e0 + e1 + e2;
    for (int o = 32; o > 0; o >>= 1) s += __shfl_xor(s, o);
    float inv = 1.0f / s;
    float* orow = C + (size_t)tok * ESL;
    orow[lane] = e0 * inv;
    orow[lane + 64] = e1 * inv;
    if (has2) orow[lane + 128] = e2 * inv;
}

// ---------------- generic tiled fp32 GEMM ----------------
// C[row, n] = sum_k A[row, k] * W[k, n] (+bias[n]) (act)
// row remap (A and C): phys_row = (r / sub) * outer + (r % sub); batch via ptr strides.
#define GTM 64
#define GTN 64
#define GTK 16

__global__ __launch_bounds__(256)
void gemm_k(const float* __restrict__ A, long long aBS, int lda, int aSub, int aOuter,
            const float* __restrict__ W, long long wBS, int ldw,
            const float* __restrict__ bias, long long biasBS,
            float* __restrict__ C, long long cBS, int ldc, int cSub, int cOuter,
            int M, int N, int K, int act) {
    A += (long long)blockIdx.z * aBS;
    W += (long long)blockIdx.z * wBS;
    if (bias != nullptr) bias += (long long)blockIdx.z * biasBS;
    C += (long long)blockIdx.z * cBS;

    __shared__ float As[GTK][GTM + 4];   // As[k][m], +4 pad keeps float4 rows 16B-aligned
    __shared__ float Ws[GTK][GTN];

    int tid = threadIdx.x;
    int tx = tid & 15, ty = tid >> 4;
    int m0 = blockIdx.y * GTM, n0 = blockIdx.x * GTN;

    // A load: thread -> row am (0..63), float4 chunk akq (0..3)
    int am = tid >> 2, akq = tid & 3;
    int arow_g = m0 + am;
    bool arow_ok = arow_g < M;
    int aq = arow_g / aSub;
    long long aoff = (long long)(aq * aOuter + (arow_g - aq * aSub)) * lda;

    // W load: thread -> col wn (0..63), 4 k-rows starting wg*4
    int wn = tid & 63, wg = tid >> 6;
    bool wcol_ok = (n0 + wn) < N;

    float acc[4][4] = {{0.f}};

    for (int k0 = 0; k0 < K; k0 += GTK) {
        float4 av = make_float4(0.f, 0.f, 0.f, 0.f);
        int ak = k0 + akq * 4;
        if (arow_ok && ak < K) av = *(const float4*)(A + aoff + ak);
        As[akq * 4 + 0][am] = av.x;
        As[akq * 4 + 1][am] = av.y;
        As[akq * 4 + 2][am] = av.z;
        As[akq * 4 + 3][am] = av.w;
#pragma unroll
        for (int jj = 0; jj < 4; ++jj) {
            int kk = wg * 4 + jj;
            float wv = 0.f;
            if (wcol_ok && (k0 + kk) < K) wv = W[(long long)(k0 + kk) * ldw + n0 + wn];
            Ws[kk][wn] = wv;
        }
        __syncthreads();
#pragma unroll
        for (int kk = 0; kk < GTK; ++kk) {
            const float4 a4 = *(const float4*)(&As[kk][ty * 4]);
            const float4 w4 = *(const float4*)(&Ws[kk][tx * 4]);
            float a[4] = {a4.x, a4.y, a4.z, a4.w};
            float w[4] = {w4.x, w4.y, w4.z, w4.w};
#pragma unroll
            for (int i = 0; i < 4; ++i)
#pragma unroll
                for (int jq = 0; jq < 4; ++jq)
                    acc[i][jq] = fmaf(a[i], w[jq], acc[i][jq]);
        }
        __syncthreads();
    }

    int col = n0 + tx * 4;
    bool col_ok = col < N;   // all N are multiples of 4
    float4 bv = make_float4(0.f, 0.f, 0.f, 0.f);
    if (bias != nullptr && col_ok) bv = *(const float4*)(bias + col);
#pragma unroll
    for (int i = 0; i < 4; ++i) {
        int row = m0 + ty * 4 + i;
        if (row < M && col_ok) {
            int q = row / cSub;
            long long coff = (long long)(q * cOuter + (row - q * cSub)) * ldc + col;
            float4 v = make_float4(acc[i][0] + bv.x, acc[i][1] + bv.y,
                                   acc[i][2] + bv.z, acc[i][3] + bv.w);
            if (act == 1) { v.x = gelu_f(v.x); v.y = gelu_f(v.y); v.z = gelu_f(v.z); v.w = gelu_f(v.w); }
            *(float4*)(C + coff) = v;
        }
    }
}

static inline void launch_gemm(hipStream_t st,
                               const float* A, long long aBS, int lda, int aSub, int aOuter,
                               const float* W, long long wBS, int ldw,
                               const float* bias, long long biasBS,
                               float* C, long long cBS, int ldc, int cSub, int cOuter,
                               int M, int N, int K, int act, int batch) {
    dim3 grid((N + GTN - 1) / GTN, (M + GTM - 1) / GTM, batch);
    gemm_k<<<grid, dim3(256), 0, st>>>(A, aBS, lda, aSub, aOuter, W, wBS, ldw,
                                       bias, biasBS, C, cBS, ldc, cSub, cOuter, M, N, K, act);
}

// ---------------- launcher ----------------
extern "C" void kernel_launch(void* const* d_in, const int* in_sizes, int n_in,
                              void* d_out, int out_size, void* d_ws, size_t ws_size,
                              hipStream_t stream) {
    const float* x     = (const float*)d_in[0];
    const float* aw    = (const float*)d_in[1];
    const float* gamma = (const float*)d_in[2];
    const float* beta  = (const float*)d_in[3];
    const float* vsg_w = (const float*)d_in[4];
    const float* vsg_b = (const float*)d_in[5];
    const float* mu    = (const float*)d_in[6];
    const float* scale = (const float*)d_in[7];
    const float* w1    = (const float*)d_in[8];
    const float* b1    = (const float*)d_in[9];
    const float* w2    = (const float*)d_in[10];
    const float* b2    = (const float*)d_in[11];
    const float* cw1   = (const float*)d_in[12];
    const float* cb1   = (const float*)d_in[13];
    const float* cw2   = (const float*)d_in[14];
    const float* cb2   = (const float*)d_in[15];
    float* out = (float*)d_out;

    const int BIG = 1 << 30;
    float* ws = (float*)d_ws;
    size_t o = 0;
    float* mu_p      = ws + o; o += (size_t)DIM * ESL;        // 101376
    float* slot_bias = ws + o; o += (size_t)NB * DIM;         // 196608
    float* t2        = ws + o; o += NTOK;                     // 32768
    float* logits    = ws + o; o += (size_t)NTOK * ESL;       // 4.3M
    float* dT        = ws + o; o += (size_t)NB * ESL * NIMG;  // 4.3M
    float* comb      = ws + o; o += (size_t)NTOK * ESL;       // 4.3M
    float* slot_in   = ws + o; o += (size_t)NB * ESL * DIM;   // 26M  (slot_out aliases this)
    float* h         = ws + o; o += (size_t)NB * ESL * NH;    // 34.6M
    float* cls_h     = ws + o; o += (size_t)NB * 4 * DIM;     // 0.8M
    float* slot_out  = slot_in;   // slot_in dead once h is built

    float* img_n = out;  // d_out as scratch; dead before final writes; fully overwritten

    repack_mu_k<<<(DIM * ESL + 255) / 256, 256, 0, stream>>>(mu, mu_p);
    slot_bias_k<<<NB, 256, 0, stream>>>(x, aw, vsg_w, vsg_b, slot_bias);
    ln_t2_k<<<NTOK, 256, 0, stream>>>(x, gamma, beta, slot_bias, img_n, t2);

    // t1[tok, es] = img_n @ mu_p : (32768x768)@(768x132)
    launch_gemm(stream, img_n, 0, DIM, BIG, 0,
                mu_p, 0, ESL, nullptr, 0,
                logits, 0, ESL, BIG, 0,
                NTOK, ESL, DIM, 0, 1);

    mask_k<<<(NTOK * ESL + 255) / 256, 256, 0, stream>>>(logits, t2, aw, scale);
    dispatch_k<<<dim3(ESL, NB), 128, 0, stream>>>(logits, dT);
    combine_k<<<NTOK, 64, 0, stream>>>(logits, comb);

    // slot_in[b] = dT[b](132x128) @ img[b](128x768)
    launch_gemm(stream, dT, (long long)ESL * NIMG, NIMG, BIG, 0,
                x + DIM, (long long)129 * DIM, DIM, nullptr, 0,
                slot_in, (long long)ESL * DIM, DIM, BIG, 0,
                ESL, DIM, NIMG, 0, NB);

    // h = gelu(slot_in @ w1[e] + b1[e]) : per e, M = NB*NS = 11264, rows remapped (r/44)*132 + r%44
    launch_gemm(stream, slot_in, (long long)NS * DIM, DIM, NS, ESL,
                w1, (long long)DIM * NH, NH, b1, NH,
                h, (long long)NS * NH, NH, NS, ESL,
                NB * NS, NH, DIM, 1, NE);

    // slot_out = h @ w2[e] + b2[e]
    launch_gemm(stream, h, (long long)NS * NH, NH, NS, ESL,
                w2, (long long)NH * DIM, DIM, b2, DIM,
                slot_out, (long long)NS * DIM, DIM, NS, ESL,
                NB * NS, DIM, NH, 0, NE);

    // img_out[b] = comb[b](128x132) @ slot_flat[b](132x768) -> out rows (b*129+1+n)
    launch_gemm(stream, comb, (long long)NIMG * ESL, ESL, BIG, 0,
                slot_out, (long long)ESL * DIM, DIM, nullptr, 0,
                out + DIM, (long long)129 * DIM, DIM, BIG, 0,
                NIMG, DIM, ESL, 0, NB);

    // cls path: cls_h = gelu(cls @ cw1 + cb1); cls_out = cls_h @ cw2 + cb2 -> out row b*129
    launch_gemm(stream, x, 0, 129 * DIM, BIG, 0,
                cw1, 0, 4 * DIM, cb1, 0,
                cls_h, 0, 4 * DIM, BIG, 0,
                NB, 4 * DIM, DIM, 1, 1);
    launch_gemm(stream, cls_h, 0, 4 * DIM, BIG, 0,
                cw2, 0, DIM, cb2, 0,
                out, 0, 129 * DIM, BIG, 0,
                NB, DIM, 4 * DIM, 0, 1);
}

// Round 2
// 1077.409 us; speedup vs baseline: 2.5737x; 2.5737x over previous
//
#include <hip/hip_runtime.h>
#include <hip/hip_bf16.h>
#include <math.h>

#define NB   256
#define NIMG 128
#define DIM  768
#define NE   3
#define NS   44
#define NH   1024
#define ESL  132          // NE*NS
#define NTOK (NB*NIMG)    // 32768
#define MAXSLOTS 88
#define BIGI (1 << 30)

typedef __bf16 bf16x8 __attribute__((ext_vector_type(8)));
typedef float f32x4 __attribute__((ext_vector_type(4)));
typedef unsigned short us8 __attribute__((ext_vector_type(8)));

// ---------------- helpers ----------------
__device__ __forceinline__ float gelu_f(float v) {
    return 0.5f * v * (1.0f + erff(v * 0.70710678118654752f));
}

__device__ __forceinline__ float block_reduce_sum256(float v, float* red) {
    int tid = threadIdx.x;
    red[tid] = v;
    __syncthreads();
    for (int s = 128; s > 0; s >>= 1) {
        if (tid < s) red[tid] += red[tid + s];
        __syncthreads();
    }
    float r = red[0];
    __syncthreads();
    return r;
}

// ---------------- repack mu: (e,d,88) -> Bt[r=e*44+s][d], bf16, padded to 256 rows ----------------
__global__ void repack_mu_k(const float* __restrict__ mu, __hip_bfloat16* __restrict__ bt) {
    int idx = blockIdx.x * 256 + threadIdx.x;
    if (idx >= 256 * DIM) return;
    int r = idx / DIM, d = idx - r * DIM;
    float v = 0.f;
    if (r < ESL) {
        int e = r / NS, s = r - e * NS;
        v = mu[((size_t)e * DIM + d) * MAXSLOTS + s];
    }
    bt[idx] = __float2bfloat16(v);
}

// ---------------- fp32 (R x Cc) -> bf16 (Cc x R) transpose, batched ----------------
__global__ void transpose_bf16_k(const float* __restrict__ in, __hip_bfloat16* __restrict__ outp,
                                 int R, int Cc) {
    __shared__ float t[32][33];
    in   += (size_t)blockIdx.z * R * Cc;
    outp += (size_t)blockIdx.z * R * Cc;
    int c0 = blockIdx.x * 32, r0 = blockIdx.y * 32;
    int tx = threadIdx.x, ty = threadIdx.y;   // 32 x 8
    for (int i = 0; i < 32; i += 8) {
        int r = r0 + ty + i, c = c0 + tx;
        t[ty + i][tx] = (r < R && c < Cc) ? in[(size_t)r * Cc + c] : 0.f;
    }
    __syncthreads();
    for (int i = 0; i < 32; i += 8) {
        int r = c0 + ty + i, c = r0 + tx;     // out is Cc x R
        if (r < Cc && c < R) outp[(size_t)r * R + c] = __float2bfloat16(t[tx][ty + i]);
    }
}

// ---------------- cls rows -> bf16 copy ----------------
__global__ void cls_bf16_k(const float* __restrict__ x, __hip_bfloat16* __restrict__ cls16) {
    int idx = blockIdx.x * 256 + threadIdx.x;
    if (idx >= NB * DIM) return;
    int b = idx / DIM, j = idx - b * DIM;
    cls16[idx] = __float2bfloat16(x[(size_t)b * 129 * DIM + j]);
}

// ---------------- slot_bias[b,:] = cls@vsg_w[:768] + af*vsg_w[768] + vsg_b ----------------
__global__ void slot_bias_k(const float* __restrict__ x, const float* __restrict__ aw,
                            const float* __restrict__ vsg_w, const float* __restrict__ vsg_b,
                            float* __restrict__ slot_bias) {
    __shared__ float red[256];
    __shared__ float cls[DIM];
    int b = blockIdx.x, tid = threadIdx.x;
    float a = (tid < NIMG) ? aw[b * NIMG + tid] : 0.f;
    float af = block_reduce_sum256(a, red) * (1.0f / NIMG);
    for (int j = tid; j < DIM; j += 256) cls[j] = x[(size_t)b * 129 * DIM + j];
    __syncthreads();
    int j0 = tid, j1 = tid + 256, j2 = tid + 512;
    float acc0 = 0.f, acc1 = 0.f, acc2 = 0.f;
    for (int d = 0; d < DIM; ++d) {
        float c = cls[d];
        const float* wr = vsg_w + (size_t)d * DIM;
        acc0 = fmaf(c, wr[j0], acc0);
        acc1 = fmaf(c, wr[j1], acc1);
        acc2 = fmaf(c, wr[j2], acc2);
    }
    const float* wl = vsg_w + (size_t)DIM * DIM;
    float* out = slot_bias + (size_t)b * DIM;
    out[j0] = acc0 + vsg_b[j0] + af * wl[j0];
    out[j1] = acc1 + vsg_b[j1] + af * wl[j1];
    out[j2] = acc2 + vsg_b[j2] + af * wl[j2];
}

// ---------------- LayerNorm (bf16 out) + t2 = dot(img_n, slot_bias[b]) ----------------
__global__ void ln_t2_k(const float* __restrict__ x, const float* __restrict__ gamma,
                        const float* __restrict__ beta, const float* __restrict__ slot_bias,
                        __hip_bfloat16* __restrict__ img_n, float* __restrict__ t2) {
    __shared__ float red[256];
    int tok = blockIdx.x;
    int b = tok >> 7, n = tok & 127;
    int tid = threadIdx.x;
    const float* row = x + ((size_t)b * 129 + 1 + n) * DIM;
    float v0 = row[tid], v1 = row[tid + 256], v2 = row[tid + 512];
    float s  = block_reduce_sum256(v0 + v1 + v2, red);
    float ss = block_reduce_sum256(v0*v0 + v1*v1 + v2*v2, red);
    float mean = s * (1.0f / DIM);
    float var  = ss * (1.0f / DIM) - mean * mean;
    float inv  = rsqrtf(var + 1e-5f);
    const float* sb = slot_bias + (size_t)b * DIM;
    __hip_bfloat16* orow = img_n + (size_t)tok * DIM;
    float tacc = 0.f;
    int j = tid;
    float y0 = (v0 - mean) * inv * gamma[j] + beta[j]; orow[j] = __float2bfloat16(y0); tacc = fmaf(y0, sb[j], tacc);
    j = tid + 256;
    float y1 = (v1 - mean) * inv * gamma[j] + beta[j]; orow[j] = __float2bfloat16(y1); tacc = fmaf(y1, sb[j], tacc);
    j = tid + 512;
    float y2 = (v2 - mean) * inv * gamma[j] + beta[j]; orow[j] = __float2bfloat16(y2); tacc = fmaf(y2, sb[j], tacc);
    float t = block_reduce_sum256(tacc, red);
    if (tid == 0) t2[tok] = t;
}

// ---------------- masked logits: L = (e==sel) ? scale*(t1+t2) : 0 ----------------
__global__ void mask_k(float* __restrict__ L, const float* __restrict__ t2,
                       const float* __restrict__ aw, const float* __restrict__ scale) {
    int idx = blockIdx.x * 256 + threadIdx.x;
    if (idx >= NTOK * ESL) return;
    int tok = idx / ESL, r = idx - tok * ESL;
    int e = r / NS;
    float a = aw[tok];
    int sel = (a > 0.7f) ? 0 : ((a >= 0.3f) ? 1 : 2);
    float v = 0.f;
    if (e == sel) v = scale[0] * (L[idx] + t2[tok]);
    L[idx] = v;
}

// ---------------- dispatch softmax over n (axis=1), output transposed [b, es, n] ----------------
__global__ void dispatch_k(const float* __restrict__ L, float* __restrict__ dT) {
    __shared__ float red[128];
    int es = blockIdx.x, b = blockIdx.y, tid = threadIdx.x;  // 128 threads
    float v = L[((size_t)(b * NIMG + tid)) * ESL + es];
    red[tid] = v; __syncthreads();
    for (int s = 64; s > 0; s >>= 1) { if (tid < s) red[tid] = fmaxf(red[tid], red[tid + s]); __syncthreads(); }
    float mx = red[0]; __syncthreads();
    float e = __expf(v - mx);
    red[tid] = e; __syncthreads();
    for (int s = 64; s > 0; s >>= 1) { if (tid < s) red[tid] += red[tid + s]; __syncthreads(); }
    float sum = red[0];
    dT[((size_t)b * ESL + es) * NIMG + tid] = e / sum;
}

// ---------------- combine softmax over es (132) per token ----------------
__global__ void combine_k(const float* __restrict__ L, float* __restrict__ C) {
    int tok = blockIdx.x, lane = threadIdx.x;  // 64 threads
    const float* row = L + (size_t)tok * ESL;
    float v0 = row[lane], v1 = row[lane + 64];
    bool has2 = lane < (ESL - 128);
    float v2 = has2 ? row[lane + 128] : -1e30f;
    float m = fmaxf(fmaxf(v0, v1), v2);
    for (int o = 32; o > 0; o >>= 1) m = fmaxf(m, __shfl_xor(m, o));
    float e0 = __expf(v0 - m), e1 = __expf(v1 - m);
    float e2 = has2 ? __expf(v2 - m) : 0.f;
    float s = e0 + e1 + e2;
    for (int o = 32; o > 0; o >>= 1) s += __shfl_xor(s, o);
    float inv = 1.0f / s;
    float* orow = C + (size_t)tok * ESL;
    orow[lane] = e0 * inv;
    orow[lane + 64] = e1 * inv;
    if (has2) orow[lane + 128] = e2 * inv;
}

// ---------------- bf16 MFMA GEMM: C = act(A @ Bt^T + bias) ----------------
// A: M x K bf16 row-major (M multiple of 128, K multiple of 32)
// Bt: Npad x K bf16 row-major (Npad multiple of 128); cols >= Nlim are not stored.
// C row remap: phys_row = (r/cSub)*cOuter + r%cSub ; batch base = z*cBS (in OUTPUT elems).
#define LDSS 40   // LDS row stride (elems): 80B, 16B-aligned, odd-bank spread

__global__ __launch_bounds__(256)
void mfma_gemm_k(const __hip_bfloat16* __restrict__ A_, long long aBS, int lda,
                 const __hip_bfloat16* __restrict__ Bt_, long long bBS, int ldb,
                 const float* __restrict__ bias, long long biasBS,
                 void* __restrict__ Cv, long long cBS, int ldc, int cSub, int cOuter,
                 int Nlim, int K, int act, int out_bf16)
{
    const unsigned short* A  = (const unsigned short*)A_  + (long long)blockIdx.z * aBS;
    const unsigned short* Bt = (const unsigned short*)Bt_ + (long long)blockIdx.z * bBS;
    if (bias) bias += (long long)blockIdx.z * biasBS;
    long long cbase = (long long)blockIdx.z * cBS;

    __shared__ unsigned short As[128 * LDSS];
    __shared__ unsigned short Bs[128 * LDSS];

    int tid = threadIdx.x;
    int m0 = blockIdx.y * 128, n0 = blockIdx.x * 128;

    // staging: thread -> row (tid>>2) of the tile, 8-elem chunk (tid&3)
    int srow = tid >> 2, sk = (tid & 3) * 8;
    const unsigned short* gA = A  + (long long)(m0 + srow) * lda + sk;
    const unsigned short* gB = Bt + (long long)(n0 + srow) * ldb + sk;
    int lofs  = srow * LDSS + sk;
    int lofs2 = (srow + 64) * LDSS + sk;

    int lane = tid & 63, wv = tid >> 6;
    int wm = (wv >> 1) * 64, wn = (wv & 1) * 64;
    int lrow = lane & 15, quad = lane >> 4;

    int a_off[4], b_off[4];
#pragma unroll
    for (int i = 0; i < 4; ++i) {
        a_off[i] = (wm + i * 16 + lrow) * LDSS + quad * 8;
        b_off[i] = (wn + i * 16 + lrow) * LDSS + quad * 8;
    }

    f32x4 acc[4][4] = {};

    for (int k0 = 0; k0 < K; k0 += 32) {
        us8 a0 = *(const us8*)(gA + k0);
        us8 a1 = *(const us8*)(gA + (long long)64 * lda + k0);
        us8 b0 = *(const us8*)(gB + k0);
        us8 b1 = *(const us8*)(gB + (long long)64 * ldb + k0);
        __syncthreads();
        *(us8*)(As + lofs)  = a0;
        *(us8*)(As + lofs2) = a1;
        *(us8*)(Bs + lofs)  = b0;
        *(us8*)(Bs + lofs2) = b1;
        __syncthreads();
        bf16x8 af[4], bfr[4];
#pragma unroll
        for (int i = 0; i < 4; ++i) {
            af[i]  = *(const bf16x8*)(As + a_off[i]);
            bfr[i] = *(const bf16x8*)(Bs + b_off[i]);
        }
#pragma unroll
        for (int i = 0; i < 4; ++i)
#pragma unroll
            for (int j = 0; j < 4; ++j)
                acc[i][j] = __builtin_amdgcn_mfma_f32_16x16x32_bf16(af[i], bfr[j], acc[i][j], 0, 0, 0);
    }

    float* Cf = (float*)Cv;
    __hip_bfloat16* Cb = (__hip_bfloat16*)Cv;
#pragma unroll
    for (int mi = 0; mi < 4; ++mi) {
#pragma unroll
        for (int r = 0; r < 4; ++r) {
            int row = m0 + wm + mi * 16 + quad * 4 + r;
            int q = row / cSub;
            long long rbase = cbase + (long long)(q * cOuter + (row - q * cSub)) * ldc;
#pragma unroll
            for (int ni = 0; ni < 4; ++ni) {
                int col = n0 + wn + ni * 16 + lrow;
                if (col < Nlim) {
                    float v = acc[mi][ni][r];
                    if (bias) v += bias[col];
                    if (act == 1) v = gelu_f(v);
                    if (out_bf16) Cb[rbase + col] = __float2bfloat16(v);
                    else          Cf[rbase + col] = v;
                }
            }
        }
    }
}

// ---------------- generic tiled fp32 GEMM (small/batched) ----------------
#define GTM 64
#define GTN 64
#define GTK 16

__global__ __launch_bounds__(256)
void gemm_k(const float* __restrict__ A, long long aBS, int lda, int aSub, int aOuter,
            const float* __restrict__ W, long long wBS, int ldw,
            const float* __restrict__ bias, long long biasBS,
            void* __restrict__ Cv, long long cBS, int ldc, int cSub, int cOuter,
            int M, int N, int K, int act, int out_bf16) {
    A += (long long)blockIdx.z * aBS;
    W += (long long)blockIdx.z * wBS;
    if (bias != nullptr) bias += (long long)blockIdx.z * biasBS;
    long long cbase = (long long)blockIdx.z * cBS;

    __shared__ float As[GTK][GTM + 4];
    __shared__ float Ws[GTK][GTN];

    int tid = threadIdx.x;
    int tx = tid & 15, ty = tid >> 4;
    int m0 = blockIdx.y * GTM, n0 = blockIdx.x * GTN;

    int am = tid >> 2, akq = tid & 3;
    int arow_g = m0 + am;
    bool arow_ok = arow_g < M;
    int aq = arow_g / aSub;
    long long aoff = (long long)(aq * aOuter + (arow_g - aq * aSub)) * lda;

    int wn = tid & 63, wg = tid >> 6;
    bool wcol_ok = (n0 + wn) < N;

    float acc[4][4] = {{0.f}};

    for (int k0 = 0; k0 < K; k0 += GTK) {
        float4 av = make_float4(0.f, 0.f, 0.f, 0.f);
        int ak = k0 + akq * 4;
        if (arow_ok && ak < K) av = *(const float4*)(A + aoff + ak);
        As[akq * 4 + 0][am] = av.x;
        As[akq * 4 + 1][am] = av.y;
        As[akq * 4 + 2][am] = av.z;
        As[akq * 4 + 3][am] = av.w;
#pragma unroll
        for (int jj = 0; jj < 4; ++jj) {
            int kk = wg * 4 + jj;
            float wv = 0.f;
            if (wcol_ok && (k0 + kk) < K) wv = W[(long long)(k0 + kk) * ldw + n0 + wn];
            Ws[kk][wn] = wv;
        }
        __syncthreads();
#pragma unroll
        for (int kk = 0; kk < GTK; ++kk) {
            const float4 a4 = *(const float4*)(&As[kk][ty * 4]);
            const float4 w4 = *(const float4*)(&Ws[kk][tx * 4]);
            float a[4] = {a4.x, a4.y, a4.z, a4.w};
            float w[4] = {w4.x, w4.y, w4.z, w4.w};
#pragma unroll
            for (int i = 0; i < 4; ++i)
#pragma unroll
                for (int jq = 0; jq < 4; ++jq)
                    acc[i][jq] = fmaf(a[i], w[jq], acc[i][jq]);
        }
        __syncthreads();
    }

    int col = n0 + tx * 4;
    bool col_ok = col < N;
    float4 bv = make_float4(0.f, 0.f, 0.f, 0.f);
    if (bias != nullptr && col_ok) bv = *(const float4*)(bias + col);
    float* Cf = (float*)Cv;
    __hip_bfloat16* Cb = (__hip_bfloat16*)Cv;
#pragma unroll
    for (int i = 0; i < 4; ++i) {
        int row = m0 + ty * 4 + i;
        if (row < M && col_ok) {
            int q = row / cSub;
            long long coff = cbase + (long long)(q * cOuter + (row - q * cSub)) * ldc + col;
            float4 v = make_float4(acc[i][0] + bv.x, acc[i][1] + bv.y,
                                   acc[i][2] + bv.z, acc[i][3] + bv.w);
            if (act == 1) { v.x = gelu_f(v.x); v.y = gelu_f(v.y); v.z = gelu_f(v.z); v.w = gelu_f(v.w); }
            if (out_bf16) {
                Cb[coff + 0] = __float2bfloat16(v.x);
                Cb[coff + 1] = __float2bfloat16(v.y);
                Cb[coff + 2] = __float2bfloat16(v.z);
                Cb[coff + 3] = __float2bfloat16(v.w);
            } else {
                *(float4*)(Cf + coff) = v;
            }
        }
    }
}

static inline void launch_gemm(hipStream_t st,
                               const float* A, long long aBS, int lda, int aSub, int aOuter,
                               const float* W, long long wBS, int ldw,
                               const float* bias, long long biasBS,
                               void* C, long long cBS, int ldc, int cSub, int cOuter,
                               int M, int N, int K, int act, int batch, int out_bf16) {
    dim3 grid((N + GTN - 1) / GTN, (M + GTM - 1) / GTM, batch);
    gemm_k<<<grid, dim3(256), 0, st>>>(A, aBS, lda, aSub, aOuter, W, wBS, ldw,
                                       bias, biasBS, C, cBS, ldc, cSub, cOuter, M, N, K, act, out_bf16);
}

// ---------------- launcher ----------------
extern "C" void kernel_launch(void* const* d_in, const int* in_sizes, int n_in,
                              void* d_out, int out_size, void* d_ws, size_t ws_size,
                              hipStream_t stream) {
    const float* x     = (const float*)d_in[0];
    const float* aw    = (const float*)d_in[1];
    const float* gamma = (const float*)d_in[2];
    const float* beta  = (const float*)d_in[3];
    const float* vsg_w = (const float*)d_in[4];
    const float* vsg_b = (const float*)d_in[5];
    const float* mu    = (const float*)d_in[6];
    const float* scale = (const float*)d_in[7];
    const float* w1    = (const float*)d_in[8];
    const float* b1    = (const float*)d_in[9];
    const float* w2    = (const float*)d_in[10];
    const float* b2    = (const float*)d_in[11];
    const float* cw1   = (const float*)d_in[12];
    const float* cb1   = (const float*)d_in[13];
    const float* cw2   = (const float*)d_in[14];
    const float* cb2   = (const float*)d_in[15];
    float* out = (float*)d_out;

    float* ws = (float*)d_ws;

    // ---- workspace layout (units: floats). Region R is reused: ----
    // R = [img_n(bf16, 12.58M fl) | logits(4.33M fl) | dT(4.33M fl)]  (21.23M fl)
    // h(bf16, 17.30M fl) aliases R after logits/dT are dead.
    const long long IMGN_FL = (long long)NTOK * DIM / 2;          // 12,582,912
    const long long LOG_FL  = (long long)NTOK * ESL;              //  4,325,376
    __hip_bfloat16* img_n = (__hip_bfloat16*)ws;
    float* logits = ws + IMGN_FL;
    float* dT     = ws + IMGN_FL + LOG_FL;
    __hip_bfloat16* h = (__hip_bfloat16*)ws;                       // alias (safe: img_n/logits/dT dead)
    long long o = IMGN_FL + 2 * LOG_FL;                            // 21,233,664
    float* comb = ws + o;                   o += LOG_FL;
    __hip_bfloat16* slot_in = (__hip_bfloat16*)(ws + o); o += (long long)NE * NB * NS * DIM / 2;  // bf16 (e,b*44+s,d)
    float* slot_out = ws + o;               o += (long long)NB * ESL * DIM;                       // fp32 (b,132,d)
    __hip_bfloat16* mu_p  = (__hip_bfloat16*)(ws + o); o += 256 * DIM / 2;
    float* slot_bias = ws + o;              o += NB * DIM;
    float* t2        = ws + o;              o += NTOK;
    __hip_bfloat16* w1t  = (__hip_bfloat16*)(ws + o); o += (long long)NE * NH * DIM / 2;
    __hip_bfloat16* w2t  = (__hip_bfloat16*)(ws + o); o += (long long)NE * DIM * NH / 2;
    __hip_bfloat16* cw1t = (__hip_bfloat16*)(ws + o); o += (long long)4 * DIM * DIM / 2;
    __hip_bfloat16* cw2t = (__hip_bfloat16*)(ws + o); o += (long long)4 * DIM * DIM / 2;
    __hip_bfloat16* cls16 = (__hip_bfloat16*)(ws + o); o += NB * DIM / 2;
    __hip_bfloat16* cls_h = (__hip_bfloat16*)(ws + o); o += (long long)NB * 4 * DIM / 2;

    // ---- weight prep (every call; graph-safe) ----
    repack_mu_k<<<(256 * DIM + 255) / 256, 256, 0, stream>>>(mu, mu_p);
    transpose_bf16_k<<<dim3(NH / 32, DIM / 32, NE), dim3(32, 8), 0, stream>>>(w1, w1t, DIM, NH);
    transpose_bf16_k<<<dim3(DIM / 32, NH / 32, NE), dim3(32, 8), 0, stream>>>(w2, w2t, NH, DIM);
    transpose_bf16_k<<<dim3(4 * DIM / 32, DIM / 32, 1), dim3(32, 8), 0, stream>>>(cw1, cw1t, DIM, 4 * DIM);
    transpose_bf16_k<<<dim3(DIM / 32, 4 * DIM / 32, 1), dim3(32, 8), 0, stream>>>(cw2, cw2t, 4 * DIM, DIM);
    cls_bf16_k<<<(NB * DIM + 255) / 256, 256, 0, stream>>>(x, cls16);

    // ---- scalar path ----
    slot_bias_k<<<NB, 256, 0, stream>>>(x, aw, vsg_w, vsg_b, slot_bias);
    ln_t2_k<<<NTOK, 256, 0, stream>>>(x, gamma, beta, slot_bias, img_n, t2);

    // t1 = img_n @ mu^T : (32768x768) x (256x768)^T -> logits fp32 (ldc=132, cols<132)
    mfma_gemm_k<<<dim3(2, NTOK / 128, 1), 256, 0, stream>>>(
        img_n, 0, DIM, mu_p, 0, DIM, nullptr, 0,
        logits, 0, ESL, BIGI, 0, ESL, DIM, 0, 0);

    mask_k<<<(NTOK * ESL + 255) / 256, 256, 0, stream>>>(logits, t2, aw, scale);
    dispatch_k<<<dim3(ESL, NB), 128, 0, stream>>>(logits, dT);
    combine_k<<<NTOK, 64, 0, stream>>>(logits, comb);

    // slot_in(e, b*44+s, d) bf16 = dT[b](132x128) @ img[b](128x768)
    launch_gemm(stream, dT, (long long)ESL * NIMG, NIMG, BIGI, 0,
                x + DIM, (long long)129 * DIM, DIM, nullptr, 0,
                slot_in, (long long)NS * DIM, DIM, NS, NB * NS,
                ESL, DIM, NIMG, 0, NB, 1);

    // h(e) bf16 = gelu(slot_in(e) @ w1t(e)^T + b1(e)) : M=11264, N=1024, K=768
    mfma_gemm_k<<<dim3(NH / 128, NB * NS / 128, NE), 256, 0, stream>>>(
        slot_in, (long long)NB * NS * DIM, DIM,
        w1t, (long long)NH * DIM, DIM, b1, NH,
        h, (long long)NB * NS * NH, NH, BIGI, 0, NH, DIM, 1, 1);

    // slot_out(b,132,d) fp32 = h(e) @ w2t(e)^T + b2(e) : M=11264, N=768, K=1024
    // row r=b*44+s -> phys b*132+s ; expert offset e*44 rows via cBS
    mfma_gemm_k<<<dim3(DIM / 128, NB * NS / 128, NE), 256, 0, stream>>>(
        h, (long long)NB * NS * NH, NH,
        w2t, (long long)DIM * NH, NH, b2, DIM,
        slot_out, (long long)NS * DIM, DIM, NS, ESL, DIM, NH, 0, 0);

    // img_out[b] = comb[b](128x132) @ slot_out[b](132x768) -> out rows (b*129+1+n)
    launch_gemm(stream, comb, (long long)NIMG * ESL, ESL, BIGI, 0,
                slot_out, (long long)ESL * DIM, DIM, nullptr, 0,
                out + DIM, (long long)129 * DIM, DIM, BIGI, 0,
                NIMG, DIM, ESL, 0, NB, 0);

    // cls path (MFMA): cls_h = gelu(cls16 @ cw1t^T + cb1) ; cls_out -> out rows b*129
    mfma_gemm_k<<<dim3(4 * DIM / 128, NB / 128, 1), 256, 0, stream>>>(
        cls16, 0, DIM, cw1t, 0, DIM, cb1, 0,
        cls_h, 0, 4 * DIM, BIGI, 0, 4 * DIM, DIM, 1, 1);
    mfma_gemm_k<<<dim3(DIM / 128, NB / 128, 1), 256, 0, stream>>>(
        cls_h, 0, 4 * DIM, cw2t, 0, 4 * DIM, cb2, 0,
        out, 0, DIM, 1, 129, DIM, 4 * DIM, 0, 0);
}

// Round 3
// 1055.414 us; speedup vs baseline: 2.6274x; 1.0208x over previous
//
#include <hip/hip_runtime.h>
#include <hip/hip_bf16.h>
#include <math.h>

#define NB   256
#define NIMG 128
#define DIM  768
#define NE   3
#define NS   44
#define NH   1024
#define ESL  132          // NE*NS
#define NTOK (NB*NIMG)    // 32768
#define MAXSLOTS 88
#define BIGI (1 << 30)
#define KPAD 160          // combine K padded to mult of 32

typedef __bf16 bf16x8 __attribute__((ext_vector_type(8)));
typedef float f32x4 __attribute__((ext_vector_type(4)));
typedef const __attribute__((address_space(1))) void* gas_t;
typedef __attribute__((address_space(3))) void* las_t;

// ---------------- helpers ----------------
__device__ __forceinline__ float gelu_f(float v) {
    return 0.5f * v * (1.0f + erff(v * 0.70710678118654752f));
}

__device__ __forceinline__ float block_reduce_sum256(float v, float* red) {
    int tid = threadIdx.x;
    red[tid] = v;
    __syncthreads();
    for (int s = 128; s > 0; s >>= 1) {
        if (tid < s) red[tid] += red[tid + s];
        __syncthreads();
    }
    float r = red[0];
    __syncthreads();
    return r;
}

// ---------------- repack mu: (e,d,88) -> Bt[r=e*44+s][d], bf16, padded to 256 rows ----------------
__global__ void repack_mu_k(const float* __restrict__ mu, __hip_bfloat16* __restrict__ bt) {
    int idx = blockIdx.x * 256 + threadIdx.x;
    if (idx >= 256 * DIM) return;
    int r = idx / DIM, d = idx - r * DIM;
    float v = 0.f;
    if (r < ESL) {
        int e = r / NS, s = r - e * NS;
        v = mu[((size_t)e * DIM + d) * MAXSLOTS + s];
    }
    bt[idx] = __float2bfloat16(v);
}

// ---------------- fp32 (R x Cc) -> bf16 (Cc x R) transpose, batched, general strides ----------------
__global__ void transpose_bf16_k(const float* __restrict__ in, __hip_bfloat16* __restrict__ outp,
                                 int R, int Cc, long long inBS, long long outBS) {
    __shared__ float t[32][33];
    in   += (long long)blockIdx.z * inBS;
    outp += (long long)blockIdx.z * outBS;
    int c0 = blockIdx.x * 32, r0 = blockIdx.y * 32;
    int tx = threadIdx.x, ty = threadIdx.y;   // 32 x 8
    for (int i = 0; i < 32; i += 8) {
        int r = r0 + ty + i, c = c0 + tx;
        t[ty + i][tx] = (r < R && c < Cc) ? in[(size_t)r * Cc + c] : 0.f;
    }
    __syncthreads();
    for (int i = 0; i < 32; i += 8) {
        int r = c0 + ty + i, c = r0 + tx;     // out is Cc x R
        if (r < Cc && c < R) outp[(size_t)r * R + c] = __float2bfloat16(t[tx][ty + i]);
    }
}

// ---------------- cls rows -> bf16 copy ----------------
__global__ void cls_bf16_k(const float* __restrict__ x, __hip_bfloat16* __restrict__ cls16) {
    int idx = blockIdx.x * 256 + threadIdx.x;
    if (idx >= NB * DIM) return;
    int b = idx / DIM, j = idx - b * DIM;
    cls16[idx] = __float2bfloat16(x[(size_t)b * 129 * DIM + j]);
}

// ---------------- slot_bias[b,:] = cls@vsg_w[:768] + af*vsg_w[768] + vsg_b ----------------
__global__ void slot_bias_k(const float* __restrict__ x, const float* __restrict__ aw,
                            const float* __restrict__ vsg_w, const float* __restrict__ vsg_b,
                            float* __restrict__ slot_bias) {
    __shared__ float red[256];
    __shared__ float cls[DIM];
    int b = blockIdx.x, tid = threadIdx.x;
    float a = (tid < NIMG) ? aw[b * NIMG + tid] : 0.f;
    float af = block_reduce_sum256(a, red) * (1.0f / NIMG);
    for (int j = tid; j < DIM; j += 256) cls[j] = x[(size_t)b * 129 * DIM + j];
    __syncthreads();
    int j0 = tid, j1 = tid + 256, j2 = tid + 512;
    float acc0 = 0.f, acc1 = 0.f, acc2 = 0.f;
    for (int d = 0; d < DIM; ++d) {
        float c = cls[d];
        const float* wr = vsg_w + (size_t)d * DIM;
        acc0 = fmaf(c, wr[j0], acc0);
        acc1 = fmaf(c, wr[j1], acc1);
        acc2 = fmaf(c, wr[j2], acc2);
    }
    const float* wl = vsg_w + (size_t)DIM * DIM;
    float* out = slot_bias + (size_t)b * DIM;
    out[j0] = acc0 + vsg_b[j0] + af * wl[j0];
    out[j1] = acc1 + vsg_b[j1] + af * wl[j1];
    out[j2] = acc2 + vsg_b[j2] + af * wl[j2];
}

// ---------------- LayerNorm (bf16 out) + t2 = dot(img_n, slot_bias[b]) ----------------
__global__ void ln_t2_k(const float* __restrict__ x, const float* __restrict__ gamma,
                        const float* __restrict__ beta, const float* __restrict__ slot_bias,
                        __hip_bfloat16* __restrict__ img_n, float* __restrict__ t2) {
    __shared__ float red[256];
    int tok = blockIdx.x;
    int b = tok >> 7, n = tok & 127;
    int tid = threadIdx.x;
    const float* row = x + ((size_t)b * 129 + 1 + n) * DIM;
    float v0 = row[tid], v1 = row[tid + 256], v2 = row[tid + 512];
    float s  = block_reduce_sum256(v0 + v1 + v2, red);
    float ss = block_reduce_sum256(v0*v0 + v1*v1 + v2*v2, red);
    float mean = s * (1.0f / DIM);
    float var  = ss * (1.0f / DIM) - mean * mean;
    float inv  = rsqrtf(var + 1e-5f);
    const float* sb = slot_bias + (size_t)b * DIM;
    __hip_bfloat16* orow = img_n + (size_t)tok * DIM;
    float tacc = 0.f;
    int j = tid;
    float y0 = (v0 - mean) * inv * gamma[j] + beta[j]; orow[j] = __float2bfloat16(y0); tacc = fmaf(y0, sb[j], tacc);
    j = tid + 256;
    float y1 = (v1 - mean) * inv * gamma[j] + beta[j]; orow[j] = __float2bfloat16(y1); tacc = fmaf(y1, sb[j], tacc);
    j = tid + 512;
    float y2 = (v2 - mean) * inv * gamma[j] + beta[j]; orow[j] = __float2bfloat16(y2); tacc = fmaf(y2, sb[j], tacc);
    float t = block_reduce_sum256(tacc, red);
    if (tid == 0) t2[tok] = t;
}

// ---------------- masked logits: L = (e==sel) ? scale*(t1+t2) : 0 ----------------
__global__ void mask_k(float* __restrict__ L, const float* __restrict__ t2,
                       const float* __restrict__ aw, const float* __restrict__ scale) {
    int idx = blockIdx.x * 256 + threadIdx.x;
    if (idx >= NTOK * ESL) return;
    int tok = idx / ESL, r = idx - tok * ESL;
    int e = r / NS;
    float a = aw[tok];
    int sel = (a > 0.7f) ? 0 : ((a >= 0.3f) ? 1 : 2);
    float v = 0.f;
    if (e == sel) v = scale[0] * (L[idx] + t2[tok]);
    L[idx] = v;
}

// ---------------- dispatch softmax over n (axis=1), bf16 out transposed [b, es, n] ----------------
__global__ void dispatch_k(const float* __restrict__ L, __hip_bfloat16* __restrict__ dT16) {
    __shared__ float red[128];
    int es = blockIdx.x, b = blockIdx.y, tid = threadIdx.x;  // 128 threads
    float v = L[((size_t)(b * NIMG + tid)) * ESL + es];
    red[tid] = v; __syncthreads();
    for (int s = 64; s > 0; s >>= 1) { if (tid < s) red[tid] = fmaxf(red[tid], red[tid + s]); __syncthreads(); }
    float mx = red[0]; __syncthreads();
    float e = __expf(v - mx);
    red[tid] = e; __syncthreads();
    for (int s = 64; s > 0; s >>= 1) { if (tid < s) red[tid] += red[tid + s]; __syncthreads(); }
    float sum = red[0];
    dT16[((size_t)b * ESL + es) * NIMG + tid] = __float2bfloat16(e / sum);
}

// ---------------- combine softmax over es (132) per token, bf16 out padded to 160 ----------------
__global__ void combine_k(const float* __restrict__ L, __hip_bfloat16* __restrict__ C) {
    int tok = blockIdx.x, lane = threadIdx.x;  // 64 threads
    const float* row = L + (size_t)tok * ESL;
    float v0 = row[lane], v1 = row[lane + 64];
    bool has2 = lane < (ESL - 128);
    float v2 = has2 ? row[lane + 128] : -1e30f;
    float m = fmaxf(fmaxf(v0, v1), v2);
    for (int o = 32; o > 0; o >>= 1) m = fmaxf(m, __shfl_xor(m, o));
    float e0 = __expf(v0 - m), e1 = __expf(v1 - m);
    float e2 = has2 ? __expf(v2 - m) : 0.f;
    float s = e0 + e1 + e2;
    for (int o = 32; o > 0; o >>= 1) s += __shfl_xor(s, o);
    float inv = 1.0f / s;
    __hip_bfloat16* orow = C + (size_t)tok * KPAD;
    orow[lane] = __float2bfloat16(e0 * inv);
    orow[lane + 64] = __float2bfloat16(e1 * inv);
    if (has2) orow[lane + 128] = __float2bfloat16(e2 * inv);
    else if (lane < KPAD - 128) orow[lane + 128] = __float2bfloat16(0.f);  // zero K-pad
}

// ---------------- bf16 MFMA GEMM v2: async staging + swizzled LDS ----------------
// C = act(A @ Bt^T + bias). A: Mrows x lda bf16; Bt: Nrows x ldb bf16.
// Staging rows clamped to [0, Mrows/Nrows); epilogue guarded by Mlim/Nlim.
// Normal store:    off = z*cBS + ((row/cSub)*cOuter + row%cSub)*ldc + col
// Transposed (ct): off = z*cBS + (row/cSub)*cOuter + row%cSub + col*ldc
__global__ __launch_bounds__(256)
void mfma2_k(const __hip_bfloat16* __restrict__ A_, long long aBS, int lda, int Mrows,
             const __hip_bfloat16* __restrict__ Bt_, long long bBS, int ldb, int Nrows,
             const float* __restrict__ bias, long long biasBS,
             void* __restrict__ Cv, long long cBS, int ldc, int cSub, long long cOuter,
             int Mlim, int Nlim, int K, int act, int out_bf16, int ctrans)
{
    const unsigned short* A  = (const unsigned short*)A_  + (long long)blockIdx.z * aBS;
    const unsigned short* Bt = (const unsigned short*)Bt_ + (long long)blockIdx.z * bBS;
    if (bias) bias += (long long)blockIdx.z * biasBS;
    long long cbase = (long long)blockIdx.z * cBS;

    __shared__ unsigned short As[128 * 32];   // 8 KB, row-major 128 x 32, chunk-swizzled
    __shared__ unsigned short Bs[128 * 32];

    int tid = threadIdx.x;
    int lane = tid & 63, wv = tid >> 6;
    int m0 = blockIdx.y * 128, n0 = blockIdx.x * 128;

    // staging: wave wv issues lds-load instrs j = 2wv, 2wv+1 for A and B.
    // instr j covers LDS bytes [j*1024, j*1024+1024): lane l -> offset j*1024 + l*16.
    // position p = j*64+l -> tile row r = p>>2, LDS chunk cl = p&3,
    // global chunk cg = cl ^ ((r>>1)&3)   (swizzle; makes frag ds_read_b128 2-way max)
    const unsigned short* ga[2];
    const unsigned short* gb[2];
    int ldsoff[2];
#pragma unroll
    for (int i = 0; i < 2; ++i) {
        int j = wv * 2 + i;
        int p = j * 64 + lane;
        int r = p >> 2;
        int cg = (p & 3) ^ ((r >> 1) & 3);
        int ra = m0 + r; if (ra > Mrows - 1) ra = Mrows - 1;
        int rb = n0 + r; if (rb > Nrows - 1) rb = Nrows - 1;
        ga[i] = A  + (long long)ra * lda + cg * 8;
        gb[i] = Bt + (long long)rb * ldb + cg * 8;
        ldsoff[i] = j * 512;
    }

    int lrow = lane & 15, quad = lane >> 4;
    int wm = (wv >> 1) * 64, wn = (wv & 1) * 64;
    int offA[4], offB[4];
#pragma unroll
    for (int i = 0; i < 4; ++i) {
        int rowa = wm + i * 16 + lrow;
        offA[i] = rowa * 32 + ((quad ^ ((rowa >> 1) & 3)) * 8);
        int rowb = wn + i * 16 + lrow;
        offB[i] = rowb * 32 + ((quad ^ ((rowb >> 1) & 3)) * 8);
    }

    f32x4 acc[4][4] = {};

    for (int k0 = 0; k0 < K; k0 += 32) {
        __syncthreads();   // prev iter's ds_reads done before overwrite
#pragma unroll
        for (int i = 0; i < 2; ++i) {
            __builtin_amdgcn_global_load_lds((gas_t)(ga[i] + k0), (las_t)(As + ldsoff[i]), 16, 0, 0);
            __builtin_amdgcn_global_load_lds((gas_t)(gb[i] + k0), (las_t)(Bs + ldsoff[i]), 16, 0, 0);
        }
        __syncthreads();   // loads landed (vmcnt drain)
        bf16x8 af[4], bfr[4];
#pragma unroll
        for (int i = 0; i < 4; ++i) {
            af[i]  = *(const bf16x8*)(As + offA[i]);
            bfr[i] = *(const bf16x8*)(Bs + offB[i]);
        }
#pragma unroll
        for (int i = 0; i < 4; ++i)
#pragma unroll
            for (int j = 0; j < 4; ++j)
                acc[i][j] = __builtin_amdgcn_mfma_f32_16x16x32_bf16(af[i], bfr[j], acc[i][j], 0, 0, 0);
    }

    float* Cf = (float*)Cv;
    __hip_bfloat16* Cb = (__hip_bfloat16*)Cv;
#pragma unroll
    for (int mi = 0; mi < 4; ++mi) {
#pragma unroll
        for (int r = 0; r < 4; ++r) {
            int row = m0 + wm + mi * 16 + quad * 4 + r;
            if (row >= Mlim) continue;
            int q = row / cSub;
            int sl = row - q * cSub;
            long long rb = ctrans ? (cbase + (long long)q * cOuter + sl)
                                  : (cbase + ((long long)q * cOuter + sl) * ldc);
#pragma unroll
            for (int ni = 0; ni < 4; ++ni) {
                int col = n0 + wn + ni * 16 + lrow;
                if (col < Nlim) {
                    float v = acc[mi][ni][r];
                    if (bias) v += bias[col];
                    if (act == 1) v = gelu_f(v);
                    long long off = ctrans ? (rb + (long long)col * ldc) : (rb + col);
                    if (out_bf16) Cb[off] = __float2bfloat16(v);
                    else          Cf[off] = v;
                }
            }
        }
    }
}

static inline void mfma2(hipStream_t st, dim3 grid,
                         const void* A, long long aBS, int lda, int Mrows,
                         const void* Bt, long long bBS, int ldb, int Nrows,
                         const float* bias, long long biasBS,
                         void* C, long long cBS, int ldc, int cSub, long long cOuter,
                         int Mlim, int Nlim, int K, int act, int obf, int ct) {
    mfma2_k<<<grid, dim3(256), 0, st>>>((const __hip_bfloat16*)A, aBS, lda, Mrows,
                                        (const __hip_bfloat16*)Bt, bBS, ldb, Nrows,
                                        bias, biasBS, C, cBS, ldc, cSub, cOuter,
                                        Mlim, Nlim, K, act, obf, ct);
}

// ---------------- launcher ----------------
extern "C" void kernel_launch(void* const* d_in, const int* in_sizes, int n_in,
                              void* d_out, int out_size, void* d_ws, size_t ws_size,
                              hipStream_t stream) {
    const float* x     = (const float*)d_in[0];
    const float* aw    = (const float*)d_in[1];
    const float* gamma = (const float*)d_in[2];
    const float* beta  = (const float*)d_in[3];
    const float* vsg_w = (const float*)d_in[4];
    const float* vsg_b = (const float*)d_in[5];
    const float* mu    = (const float*)d_in[6];
    const float* scale = (const float*)d_in[7];
    const float* w1    = (const float*)d_in[8];
    const float* b1    = (const float*)d_in[9];
    const float* w2    = (const float*)d_in[10];
    const float* b2    = (const float*)d_in[11];
    const float* cw1   = (const float*)d_in[12];
    const float* cb1   = (const float*)d_in[13];
    const float* cw2   = (const float*)d_in[14];
    const float* cb2   = (const float*)d_in[15];
    float* out = (float*)d_out;

    float* ws = (float*)d_ws;

    // ---- workspace (units: float). region1 = [img_n | logits], later h aliases it. ----
    const long long IMGN_FL = (long long)NTOK * DIM / 2;           // 12,582,912
    const long long LOG_FL  = (long long)NTOK * ESL;               //  4,325,376
    const long long REG1_FL = (long long)NE * NB * NS * NH / 2;    // 17,301,504 (h)
    __hip_bfloat16* img_n = (__hip_bfloat16*)ws;
    float* logits = ws + IMGN_FL;
    __hip_bfloat16* h = (__hip_bfloat16*)ws;                       // alias region1
    long long o = REG1_FL;
    __hip_bfloat16* dT16    = (__hip_bfloat16*)(ws + o); o += (long long)NB * ESL * NIMG / 2;   // 2,162,688
    __hip_bfloat16* comb_p  = (__hip_bfloat16*)(ws + o); o += (long long)NTOK * KPAD / 2;       // 2,621,440
    // region2 = imgT (then slot_outT overwrites it; sized for the larger)
    __hip_bfloat16* imgT    = (__hip_bfloat16*)(ws + o);
    __hip_bfloat16* slot_outT = imgT;                    o += (long long)NB * DIM * KPAD / 2;   // 15,728,640
    __hip_bfloat16* slot_in = (__hip_bfloat16*)(ws + o); o += (long long)NE * NB * NS * DIM / 2;// 12,976,128
    __hip_bfloat16* mu_p    = (__hip_bfloat16*)(ws + o); o += 256 * DIM / 2;
    float* slot_bias = ws + o;                           o += NB * DIM;
    float* t2        = ws + o;                           o += NTOK;
    __hip_bfloat16* w1t  = (__hip_bfloat16*)(ws + o);    o += (long long)NE * NH * DIM / 2;
    __hip_bfloat16* w2t  = (__hip_bfloat16*)(ws + o);    o += (long long)NE * DIM * NH / 2;
    __hip_bfloat16* cw1t = (__hip_bfloat16*)(ws + o);    o += (long long)4 * DIM * DIM / 2;
    __hip_bfloat16* cw2t = (__hip_bfloat16*)(ws + o);    o += (long long)4 * DIM * DIM / 2;
    __hip_bfloat16* cls16 = (__hip_bfloat16*)(ws + o);   o += NB * DIM / 2;
    __hip_bfloat16* cls_h = (__hip_bfloat16*)(ws + o);   o += (long long)NB * 4 * DIM / 2;

    // ---- prep (every call; graph-safe) ----
    repack_mu_k<<<(256 * DIM + 255) / 256, 256, 0, stream>>>(mu, mu_p);
    transpose_bf16_k<<<dim3(NH / 32, DIM / 32, NE), dim3(32, 8), 0, stream>>>(w1, w1t, DIM, NH, (long long)DIM * NH, (long long)NH * DIM);
    transpose_bf16_k<<<dim3(DIM / 32, NH / 32, NE), dim3(32, 8), 0, stream>>>(w2, w2t, NH, DIM, (long long)NH * DIM, (long long)DIM * NH);
    transpose_bf16_k<<<dim3(4 * DIM / 32, DIM / 32, 1), dim3(32, 8), 0, stream>>>(cw1, cw1t, DIM, 4 * DIM, 0, 0);
    transpose_bf16_k<<<dim3(DIM / 32, 4 * DIM / 32, 1), dim3(32, 8), 0, stream>>>(cw2, cw2t, 4 * DIM, DIM, 0, 0);
    cls_bf16_k<<<(NB * DIM + 255) / 256, 256, 0, stream>>>(x, cls16);
    // imgT[b] (768 x 128) = img[b]^T
    transpose_bf16_k<<<dim3(DIM / 32, NIMG / 32, NB), dim3(32, 8), 0, stream>>>(x + DIM, imgT, NIMG, DIM, (long long)129 * DIM, (long long)DIM * NIMG);

    // ---- scalar path ----
    slot_bias_k<<<NB, 256, 0, stream>>>(x, aw, vsg_w, vsg_b, slot_bias);
    ln_t2_k<<<NTOK, 256, 0, stream>>>(x, gamma, beta, slot_bias, img_n, t2);

    // t1 = img_n @ mu_p^T : (32768x768) x (256x768)^T -> logits fp32 (ldc=132)
    mfma2(stream, dim3(2, NTOK / 128, 1),
          img_n, 0, DIM, NTOK, mu_p, 0, DIM, 256, nullptr, 0,
          logits, 0, ESL, BIGI, 0, NTOK, ESL, DIM, 0, 0, 0);

    mask_k<<<(NTOK * ESL + 255) / 256, 256, 0, stream>>>(logits, t2, aw, scale);
    dispatch_k<<<dim3(ESL, NB), 128, 0, stream>>>(logits, dT16);
    combine_k<<<NTOK, 64, 0, stream>>>(logits, comb_p);

    // slot_in(e, b*44+s, d) bf16 = dT16[b](132x128) @ imgT[b]^T ; M=132 (clamped), batch=NB
    mfma2(stream, dim3(DIM / 128, 2, NB),
          dT16, (long long)ESL * NIMG, NIMG, ESL,
          imgT, (long long)DIM * NIMG, NIMG, DIM, nullptr, 0,
          slot_in, (long long)NS * DIM, DIM, NS, NB * NS,
          ESL, DIM, NIMG, 0, 1, 0);

    // h(e) = gelu(slot_in(e) @ w1t(e)^T + b1(e)) : M=11264, N=1024, K=768
    mfma2(stream, dim3(NH / 128, NB * NS / 128, NE),
          slot_in, (long long)NB * NS * DIM, DIM, NB * NS,
          w1t, (long long)NH * DIM, DIM, NH, b1, NH,
          h, (long long)NB * NS * NH, NH, BIGI, 0,
          NB * NS, NH, DIM, 1, 1, 0);

    // slot_outT[b](768 x 160) bf16 = (h(e) @ w2t(e)^T + b2(e)) stored TRANSPOSED
    // row r=b*44+s (expert e): off = e*44 + b*(768*160) + d*160 + s
    mfma2(stream, dim3(DIM / 128, NB * NS / 128, NE),
          h, (long long)NB * NS * NH, NH, NB * NS,
          w2t, (long long)DIM * NH, NH, DIM, b2, DIM,
          slot_outT, NS, KPAD, NS, (long long)DIM * KPAD,
          NB * NS, DIM, NH, 0, 1, 1);

    // img_out[b](128x768) = comb_p[b](128x160) @ slot_outT[b](768x160)^T -> out rows b*129+1+n
    mfma2(stream, dim3(DIM / 128, 1, NB),
          comb_p, (long long)NIMG * KPAD, KPAD, NIMG,
          slot_outT, (long long)DIM * KPAD, KPAD, DIM, nullptr, 0,
          out + DIM, (long long)129 * DIM, DIM, BIGI, 0,
          NIMG, DIM, KPAD, 0, 0, 0);

    // cls path: cls_h = gelu(cls16 @ cw1t^T + cb1) ; cls_out -> out rows b*129
    mfma2(stream, dim3(4 * DIM / 128, NB / 128, 1),
          cls16, 0, DIM, NB, cw1t, 0, DIM, 4 * DIM, cb1, 0,
          cls_h, 0, 4 * DIM, BIGI, 0, NB, 4 * DIM, DIM, 1, 1, 0);
    mfma2(stream, dim3(DIM / 128, NB / 128, 1),
          cls_h, 0, 4 * DIM, NB, cw2t, 0, 4 * DIM, DIM, cb2, 0,
          out, 0, DIM, 1, 129, NB, DIM, 4 * DIM, 0, 0, 0);
}